// Round 1
// baseline (47.136 us; speedup 1.0000x reference)
//
#include <hip/hip_runtime.h>
#include <hip/hip_bf16.h>

#define NPTS  262144
#define UNITS 256
#define TPB   256
#define NBLK  512   // NBLK * TPB * 2 points == NPTS

#if defined(__has_builtin)
#if __has_builtin(__builtin_amdgcn_exp2f)
#define HAVE_AMD_EXP2 1
#endif
#endif

__device__ __forceinline__ float fexp2(float x) {
#ifdef HAVE_AMD_EXP2
    return __builtin_amdgcn_exp2f(x);
#else
    return exp2f(x);
#endif
}

__global__ __launch_bounds__(TPB) void rbf_main(
    const float* __restrict__ gx, const float* __restrict__ gy,
    const float* __restrict__ gu, const float* __restrict__ gv,
    const float* __restrict__ gdu, const float* __restrict__ gdv,
    const float* __restrict__ mu_u, const float* __restrict__ beta_u,
    const float* __restrict__ W_u,
    const float* __restrict__ mu_v, const float* __restrict__ beta_v,
    const float* __restrict__ W_v,
    const float* __restrict__ p_d, const float* __restrict__ p_a,
    const float* __restrict__ p_b, const float* __restrict__ p_um,
    const float* __restrict__ p_vm, const float* __restrict__ p_us,
    const float* __restrict__ p_vs,
    float* __restrict__ part)
{
    const int tid = threadIdx.x;
    const int bid = blockIdx.x;
    const int i0  = bid * TPB + tid;
    const int i1  = i0 + NBLK * TPB;

    const float x0 = gx[i0], y0 = gy[i0];
    const float x1 = gx[i1], y1 = gy[i1];

    float up0 = 0.f, lu0 = 0.f, vp0 = 0.f, lv0 = 0.f;
    float up1 = 0.f, lu1 = 0.f, vp1 = 0.f, lv1 = 0.f;

    const float LOG2E = 1.4426950408889634f;
    const float LN2   = 0.6931471805599453f;

    // phi = exp(-b*r2) = exp2(-(b*log2e)*r2);  g = (b*log2e)*r2
    // lap coeff c = 4*b^2*r2 - 4*b = fma(4b*ln2, g, -4b)
    #pragma unroll 4
    for (int j = 0; j < UNITS; ++j) {
        {
            const float mx = mu_u[j], my = mu_u[UNITS + j];
            const float b  = beta_u[j], w = W_u[j];
            const float bp = b * LOG2E;
            const float b4 = 4.0f * b;
            const float c1 = b4 * LN2;

            float dx = x0 - mx, dy = y0 - my;
            float r2 = fmaf(dx, dx, dy * dy);
            float g  = bp * r2;
            float ph = fexp2(-g);
            float pw = ph * w;
            up0 += pw;
            float c  = fmaf(c1, g, -b4);
            lu0 = fmaf(pw, c, lu0);

            dx = x1 - mx; dy = y1 - my;
            r2 = fmaf(dx, dx, dy * dy);
            g  = bp * r2;
            ph = fexp2(-g);
            pw = ph * w;
            up1 += pw;
            c  = fmaf(c1, g, -b4);
            lu1 = fmaf(pw, c, lu1);
        }
        {
            const float mx = mu_v[j], my = mu_v[UNITS + j];
            const float b  = beta_v[j], w = W_v[j];
            const float bp = b * LOG2E;
            const float b4 = 4.0f * b;
            const float c1 = b4 * LN2;

            float dx = x0 - mx, dy = y0 - my;
            float r2 = fmaf(dx, dx, dy * dy);
            float g  = bp * r2;
            float ph = fexp2(-g);
            float pw = ph * w;
            vp0 += pw;
            float c  = fmaf(c1, g, -b4);
            lv0 = fmaf(pw, c, lv0);

            dx = x1 - mx; dy = y1 - my;
            r2 = fmaf(dx, dx, dy * dy);
            g  = bp * r2;
            ph = fexp2(-g);
            pw = ph * w;
            vp1 += pw;
            c  = fmaf(c1, g, -b4);
            lv1 = fmaf(pw, c, lv1);
        }
    }

    // ---- residuals ----
    const float d  = p_d[0],  a = p_a[0],  b = p_b[0];
    const float um = p_um[0], vm = p_vm[0];
    const float us = p_us[0], vs = p_vs[0];
    const float iu  = 1.0f / us, iv = 1.0f / vs;
    const float cau = (a - um) * iu;        // a/us - um/us
    const float c4b = 4.0f * b * iu;        // 4b/us
    const float cbv = b * iv;               // b/vs

    float s0 = 0.f, s1 = 0.f, s2 = 0.f, s3 = 0.f, s4 = 0.f, s5 = 0.f;

    {   // point 0
        const float uu = gu[i0], vv = gv[i0];
        const float ddu = gdu[i0], ddv = gdv[i0];
        float eu = up0 - uu; s0 += eu * eu;
        float ev = vp0 - vv; s1 += ev * ev;
        float uph = fmaf(up0, us, um);
        float vph = fmaf(vp0, vs, vm);
        float den = fmaf(uph, uph, 1.0f);
        float uvd = uph * vph / den;
        float rpu = fmaf(d, lu0, cau) - up0 - c4b * uvd;
        s2 += rpu * rpu;
        float rdu = lu0 - ddu; s3 += rdu * rdu;
        float rpv = fmaf(uph, iv, lv0) - cbv * uvd;
        s4 += rpv * rpv;
        float rdv = lv0 - ddv; s5 += rdv * rdv;
    }
    {   // point 1
        const float uu = gu[i1], vv = gv[i1];
        const float ddu = gdu[i1], ddv = gdv[i1];
        float eu = up1 - uu; s0 += eu * eu;
        float ev = vp1 - vv; s1 += ev * ev;
        float uph = fmaf(up1, us, um);
        float vph = fmaf(vp1, vs, vm);
        float den = fmaf(uph, uph, 1.0f);
        float uvd = uph * vph / den;
        float rpu = fmaf(d, lu1, cau) - up1 - c4b * uvd;
        s2 += rpu * rpu;
        float rdu = lu1 - ddu; s3 += rdu * rdu;
        float rpv = fmaf(uph, iv, lv1) - cbv * uvd;
        s4 += rpv * rpv;
        float rdv = lv1 - ddv; s5 += rdv * rdv;
    }

    // ---- block reduction (deterministic) ----
    float s[6] = { s0, s1, s2, s3, s4, s5 };
    __shared__ float red[4][6];
    #pragma unroll
    for (int k = 0; k < 6; ++k) {
        float vsum = s[k];
        for (int off = 32; off > 0; off >>= 1)
            vsum += __shfl_down(vsum, off);
        s[k] = vsum;
    }
    const int lane = tid & 63;
    const int wid  = tid >> 6;
    if (lane == 0) {
        #pragma unroll
        for (int k = 0; k < 6; ++k) red[wid][k] = s[k];
    }
    __syncthreads();
    if (tid < 6) {
        float p = red[0][tid] + red[1][tid] + red[2][tid] + red[3][tid];
        part[tid * NBLK + bid] = p;
    }
}

__global__ __launch_bounds__(256) void rbf_final(
    const float* __restrict__ part, float* __restrict__ out)
{
    const int tid = threadIdx.x;
    __shared__ float red[4][6];
    float s[6];
    #pragma unroll
    for (int k = 0; k < 6; ++k) {
        float vsum = part[k * NBLK + tid] + part[k * NBLK + tid + 256];
        for (int off = 32; off > 0; off >>= 1)
            vsum += __shfl_down(vsum, off);
        s[k] = vsum;
    }
    const int lane = tid & 63;
    const int wid  = tid >> 6;
    if (lane == 0) {
        #pragma unroll
        for (int k = 0; k < 6; ++k) red[wid][k] = s[k];
    }
    __syncthreads();
    if (tid == 0) {
        const float inv = 1.0f / (float)NPTS;
        const float Lu  = (red[0][0] + red[1][0] + red[2][0] + red[3][0]) * inv;
        const float Lv  = (red[0][1] + red[1][1] + red[2][1] + red[3][1]) * inv;
        const float Lpu = (red[0][2] + red[1][2] + red[2][2] + red[3][2]) * inv;
        const float Ldu = (red[0][3] + red[1][3] + red[2][3] + red[3][3]) * inv;
        const float Lpv = (red[0][4] + red[1][4] + red[2][4] + red[3][4]) * inv;
        const float Ldv = (red[0][5] + red[1][5] + red[2][5] + red[3][5]) * inv;
        out[0] = 0.1f * Lu + 0.1f * Lv + Lpu + Ldu + Lpv + Ldv;
        out[1] = Lu;
        out[2] = Lpu;
        out[3] = Lv;
        out[4] = Lpv;
        out[5] = Ldu;
        out[6] = Ldv;
    }
}

extern "C" void kernel_launch(void* const* d_in, const int* in_sizes, int n_in,
                              void* d_out, int out_size, void* d_ws, size_t ws_size,
                              hipStream_t stream) {
    const float* gx   = (const float*)d_in[0];
    const float* gy   = (const float*)d_in[1];
    const float* gu   = (const float*)d_in[2];
    const float* gv   = (const float*)d_in[3];
    const float* gdu  = (const float*)d_in[4];
    const float* gdv  = (const float*)d_in[5];
    const float* mu_u = (const float*)d_in[6];
    const float* be_u = (const float*)d_in[7];
    const float* W_u  = (const float*)d_in[8];
    const float* mu_v = (const float*)d_in[9];
    const float* be_v = (const float*)d_in[10];
    const float* W_v  = (const float*)d_in[11];
    const float* p_d  = (const float*)d_in[12];
    const float* p_a  = (const float*)d_in[13];
    const float* p_b  = (const float*)d_in[14];
    const float* p_um = (const float*)d_in[15];
    const float* p_vm = (const float*)d_in[16];
    const float* p_us = (const float*)d_in[17];
    const float* p_vs = (const float*)d_in[18];

    float* part = (float*)d_ws;              // 6 * NBLK floats = 12 KB
    float* out  = (float*)d_out;             // 7 floats

    rbf_main<<<NBLK, TPB, 0, stream>>>(gx, gy, gu, gv, gdu, gdv,
                                       mu_u, be_u, W_u, mu_v, be_v, W_v,
                                       p_d, p_a, p_b, p_um, p_vm, p_us, p_vs,
                                       part);
    rbf_final<<<1, 256, 0, stream>>>(part, out);
}